// Round 6
// baseline (10330.469 us; speedup 1.0000x reference)
//
#include <hip/hip_runtime.h>
#include <stdint.h>

#define NN_ 4096
#define DM_ 256
#define CAND_CAP 512

typedef unsigned short ushort_t;
typedef __bf16 bf16x8 __attribute__((ext_vector_type(8)));
typedef _Float16 f16x8 __attribute__((ext_vector_type(8)));
typedef float f32x4 __attribute__((ext_vector_type(4)));

__device__ __forceinline__ unsigned short f32_to_bf16(float x) {
  unsigned int u = __float_as_uint(x);
  unsigned int r = u + 0x7FFFu + ((u >> 16) & 1u);   // RNE
  return (unsigned short)(r >> 16);
}
__device__ __forceinline__ float bf16_to_f32(unsigned short h) {
  return __uint_as_float(((unsigned int)h) << 16);
}

// global -> LDS direct (16B/lane). LDS dest is wave-uniform base + lane*16.
__device__ __forceinline__ void async_cp16(const void* g, void* l) {
  auto gp = reinterpret_cast<__attribute__((address_space(1))) unsigned int*>(
      reinterpret_cast<uintptr_t>(g));
  auto lp = reinterpret_cast<__attribute__((address_space(3))) unsigned int*>(
      reinterpret_cast<uintptr_t>(l));
  __builtin_amdgcn_global_load_lds(gp, lp, 16, 0, 0);
}

// ---------------------------------------------------------------------------
// Kernel 1: Rt = rescale(dist)^T as fp16 hi/lo pair. Rt[p][m] = f(dist[m][p]).
// ---------------------------------------------------------------------------
__global__ __launch_bounds__(256) void rescale_kernel(const float* __restrict__ dist,
                                                      _Float16* __restrict__ Rth,
                                                      _Float16* __restrict__ Rtl) {
  __shared__ float tile[64][65];
  const int m0 = blockIdx.y * 64;
  const int p0 = blockIdx.x * 64;
  const int t = threadIdx.x;
  const int c = t & 63;
  const int rg = t >> 6;
  const float C = 3.718281828459045f;  // 1 + e
  for (int i = 0; i < 16; i++) {
    int ml = rg * 16 + i;
    float d = dist[(size_t)(m0 + ml) * NN_ + p0 + c];
    tile[c][ml] = C / (1.0f + expf(1.0f - d));  // store transposed into LDS
  }
  __syncthreads();
  for (int i = 0; i < 16; i++) {
    int pl = rg * 16 + i;
    float v = tile[pl][c];
    _Float16 hv = (_Float16)v;
    size_t o = (size_t)(p0 + pl) * NN_ + m0 + c;
    Rth[o] = hv;
    Rtl[o] = (_Float16)(v - (float)hv);
  }
}

// ---------------------------------------------------------------------------
// Kernel 2: O = X @ W^T (fp32 accum). Optional fp32 out, optional bf16 hi/lo.
// ---------------------------------------------------------------------------
__global__ __launch_bounds__(256) void proj_kernel(const float* __restrict__ X,
                                                   const float* __restrict__ W,
                                                   float* __restrict__ Of,
                                                   ushort_t* __restrict__ O1,
                                                   ushort_t* __restrict__ O2) {
  __shared__ float Xs[64][33];
  __shared__ float Ws[64][33];
  const int m0 = blockIdx.y * 64;
  const int n0 = blockIdx.x * 64;
  const int t = threadIdx.x;
  const int tm = t >> 4, tn = t & 15;
  float acc[4][4] = {};
  for (int k0 = 0; k0 < DM_; k0 += 32) {
    for (int q = 0; q < 2; q++) {
      int id = t + q * 256;
      int row = id >> 3;
      int c4 = (id & 7) * 4;
      float4 vx = *(const float4*)&X[(size_t)(m0 + row) * DM_ + k0 + c4];
      Xs[row][c4] = vx.x; Xs[row][c4 + 1] = vx.y; Xs[row][c4 + 2] = vx.z; Xs[row][c4 + 3] = vx.w;
      float4 vw = *(const float4*)&W[(size_t)(n0 + row) * DM_ + k0 + c4];
      Ws[row][c4] = vw.x; Ws[row][c4 + 1] = vw.y; Ws[row][c4 + 2] = vw.z; Ws[row][c4 + 3] = vw.w;
    }
    __syncthreads();
    for (int kk = 0; kk < 32; kk++) {
      float xi[4], wj[4];
      for (int i = 0; i < 4; i++) xi[i] = Xs[tm * 4 + i][kk];
      for (int j = 0; j < 4; j++) wj[j] = Ws[tn * 4 + j][kk];
      for (int i = 0; i < 4; i++)
        for (int j = 0; j < 4; j++) acc[i][j] += xi[i] * wj[j];
    }
    __syncthreads();
  }
  for (int i = 0; i < 4; i++)
    for (int j = 0; j < 4; j++) {
      size_t o = (size_t)(m0 + tm * 4 + i) * DM_ + n0 + tn * 4 + j;
      float v = acc[i][j];
      if (Of != nullptr) Of[o] = v;
      if (O1 != nullptr) {
        unsigned short hh = f32_to_bf16(v);
        O1[o] = hh;
        O2[o] = f32_to_bf16(v - bf16_to_f32(hh));
      }
    }
}

// ---------------------------------------------------------------------------
// Kernel 3: per head, A = relu(Q_h K_h^T)/sqrt(32), 3-product bf16 (exact-ish),
// output as fp16 hi/lo pair. Block (0,0) also zeroes rowMax/rowCnt.
// ---------------------------------------------------------------------------
__global__ __launch_bounds__(256) void qk_kernel(const ushort_t* __restrict__ Q1,
                                                 const ushort_t* __restrict__ Q2,
                                                 const ushort_t* __restrict__ K1,
                                                 const ushort_t* __restrict__ K2,
                                                 _Float16* __restrict__ Ah,
                                                 _Float16* __restrict__ Al,
                                                 float* __restrict__ rowMax,
                                                 int* __restrict__ rowCnt, int h) {
  const int n0 = blockIdx.y * 64;  // rows (n, from Q)
  const int m0 = blockIdx.x * 64;  // cols (m, from K)
  const int t = threadIdx.x;
  if (blockIdx.x == 0 && blockIdx.y == 0) {
    for (int i = t; i < NN_; i += 256) { rowMax[i] = 0.f; rowCnt[i] = 0; }
  }
  const int wave = t >> 6, lane = t & 63;
  const int wm = wave >> 1, wn = wave & 1;
  const int r16 = lane & 15, quad = lane >> 4;
  const int ho = h * 32 + quad * 8;
  f32x4 acc[2][2] = {};
  bf16x8 a1[2], a2[2], b1[2], b2[2];
  for (int i = 0; i < 2; i++) {
    int row = n0 + wm * 32 + i * 16 + r16;
    a1[i] = *(const bf16x8*)&Q1[(size_t)row * DM_ + ho];
    a2[i] = *(const bf16x8*)&Q2[(size_t)row * DM_ + ho];
  }
  for (int j = 0; j < 2; j++) {
    int col = m0 + wn * 32 + j * 16 + r16;
    b1[j] = *(const bf16x8*)&K1[(size_t)col * DM_ + ho];
    b2[j] = *(const bf16x8*)&K2[(size_t)col * DM_ + ho];
  }
  for (int i = 0; i < 2; i++)
    for (int j = 0; j < 2; j++) {
      acc[i][j] = __builtin_amdgcn_mfma_f32_16x16x32_bf16(a1[i], b1[j], acc[i][j], 0, 0, 0);
      acc[i][j] = __builtin_amdgcn_mfma_f32_16x16x32_bf16(a1[i], b2[j], acc[i][j], 0, 0, 0);
      acc[i][j] = __builtin_amdgcn_mfma_f32_16x16x32_bf16(a2[i], b1[j], acc[i][j], 0, 0, 0);
    }
  const float scale = 0.17677669529663688f;  // 1/sqrt(32)
  for (int i = 0; i < 2; i++)
    for (int j = 0; j < 2; j++)
      for (int r = 0; r < 4; r++) {
        int row = n0 + wm * 32 + i * 16 + quad * 4 + r;  // C/D: col=lane&15, row=quad*4+reg
        int col = m0 + wn * 32 + j * 16 + r16;
        float w = acc[i][j][r] * scale;
        w = w > 0.f ? w : 0.f;
        _Float16 hh = (_Float16)w;
        size_t o = (size_t)row * NN_ + col;
        Ah[o] = hh;
        Al[o] = (_Float16)(w - (float)hh);
      }
}

// ---------------------------------------------------------------------------
// Kernel 4: S~ = Ah @ Rth^T (NT, K=4096), fp16 MFMA, BK=64, 128x128 tile.
// LDS chunk-XOR swizzle: 16B chunk c of row r lives at slot c^(r&7) -> fragment
// reads hit all 8 bank groups with 2 lanes each (free); staging fetches global
// chunk cphys^srow so the data lands identically. Pure address permutation
// within the HW-verified fp16 fragment layout.
// Epilogue: atomicMax rowMax + ballot-push candidates (v > knownMax-16) into
// per-row lists. Stale rowMax reads only ADD candidates (any entry within 16
// of the final row max is always pushed: its block's thr <= finalMax-16).
// No S matrix is materialized.
// ---------------------------------------------------------------------------
__global__ __launch_bounds__(256) void sgemm_kernel(const _Float16* __restrict__ Ah,
                                                    const _Float16* __restrict__ Rth,
                                                    float* __restrict__ rowMax,
                                                    int* __restrict__ rowCnt,
                                                    int* __restrict__ CandP,
                                                    float* __restrict__ CandV) {
  __shared__ _Float16 sA[128 * 64], sB[128 * 64];  // 16 KB each
  const int m0 = blockIdx.y * 128;
  const int p0 = blockIdx.x * 128;
  const int t = threadIdx.x;
  const int wave = t >> 6, lane = t & 63;
  const int wm = wave >> 1, wn = wave & 1;
  const int r16 = lane & 15, quad = lane >> 4;
  const int srow = lane >> 3;            // 0..7 (row within 8-row staging slab)
  const int cg = (lane & 7) ^ srow;      // global 16B chunk this lane fetches
  f32x4 acc[4][4] = {};
  for (int k0 = 0; k0 < NN_; k0 += 64) {
    for (int tt = 0; tt < 4; tt++) {
      int rl = wave * 32 + tt * 8;       // wave-uniform slab base row
      async_cp16(&Ah[(size_t)(m0 + rl + srow) * NN_ + k0 + cg * 8], &sA[rl * 64]);
      async_cp16(&Rth[(size_t)(p0 + rl + srow) * NN_ + k0 + cg * 8], &sB[rl * 64]);
    }
    __syncthreads();
    f16x8 af[4][2], bg[4][2];
    for (int i = 0; i < 4; i++) {
      int r = wm * 64 + i * 16 + r16;
      int s0 = quad ^ (r & 7);
      int s1 = (4 + quad) ^ (r & 7);
      af[i][0] = *(const f16x8*)&sA[r * 64 + s0 * 8];
      af[i][1] = *(const f16x8*)&sA[r * 64 + s1 * 8];
    }
    for (int j = 0; j < 4; j++) {
      int r = wn * 64 + j * 16 + r16;
      int s0 = quad ^ (r & 7);
      int s1 = (4 + quad) ^ (r & 7);
      bg[j][0] = *(const f16x8*)&sB[r * 64 + s0 * 8];
      bg[j][1] = *(const f16x8*)&sB[r * 64 + s1 * 8];
    }
    for (int i = 0; i < 4; i++)
      for (int j = 0; j < 4; j++) {
        acc[i][j] = __builtin_amdgcn_mfma_f32_16x16x32_f16(af[i][0], bg[j][0], acc[i][j], 0, 0, 0);
        acc[i][j] = __builtin_amdgcn_mfma_f32_16x16x32_f16(af[i][1], bg[j][1], acc[i][j], 0, 0, 0);
      }
    __syncthreads();
  }
  // Epilogue: rowMax update + candidate push. C/D: col=lane&15, row=quad*4+reg.
  const unsigned long long qmask = 0xFFFFULL << (quad * 16);
  const unsigned long long below = (lane == 0) ? 0ULL : ((~0ULL) >> (64 - lane));
  for (int i = 0; i < 4; i++)
    for (int rr = 0; rr < 4; rr++) {
      float mv = fmaxf(fmaxf(acc[i][0][rr], acc[i][1][rr]),
                       fmaxf(acc[i][2][rr], acc[i][3][rr]));
      for (int off = 1; off < 16; off <<= 1) mv = fmaxf(mv, __shfl_xor(mv, off, 64));
      int row = m0 + wm * 64 + i * 16 + quad * 4 + rr;
      float cur = 0.f;
      if (r16 == 0) {
        unsigned int old = atomicMax((unsigned int*)&rowMax[row], __float_as_uint(mv));
        cur = fmaxf(__uint_as_float(old), mv);
      }
      cur = __shfl(cur, quad * 16, 64);
      float thr = cur - 16.0f;
      for (int j = 0; j < 4; j++) {
        float v = acc[i][j][rr];
        bool pred = v > thr;
        unsigned long long bal = __ballot(pred);
        unsigned long long mq = bal & qmask;
        int nq = __popcll(mq);
        int base = 0;
        if (r16 == 0 && nq > 0) base = atomicAdd(&rowCnt[row], nq);
        base = __shfl(base, quad * 16, 64);
        if (pred) {
          int idx = base + __popcll(mq & below);
          if (idx < CAND_CAP) {
            CandP[(size_t)row * CAND_CAP + idx] = p0 + wn * 64 + j * 16 + r16;
            CandV[(size_t)row * CAND_CAP + idx] = v;
          }
        }
      }
    }
}

// ---------------------------------------------------------------------------
// Kernel 5: one wave per row. Filter candidate list by final rowMax-16, exact
// fp32 dots (A pair x Rt pair), flash-style online softmax + PV, in registers.
// ---------------------------------------------------------------------------
__global__ __launch_bounds__(256) void refine_kernel(const int* __restrict__ CandP,
                                                     const float* __restrict__ CandV,
                                                     const int* __restrict__ rowCnt,
                                                     const float* __restrict__ rowMax,
                                                     const _Float16* __restrict__ Ah,
                                                     const _Float16* __restrict__ Al,
                                                     const _Float16* __restrict__ Rth,
                                                     const _Float16* __restrict__ Rtl,
                                                     const float* __restrict__ Vf,
                                                     float* __restrict__ out, int h) {
  const int t = threadIdx.x;
  const int wave = t >> 6, lane = t & 63;
  const int n = blockIdx.x * 4 + wave;
  int C = rowCnt[n];
  if (C > CAND_CAP) C = CAND_CAP;
  const float thr = rowMax[n] - 16.0f;
  const _Float16* arh = Ah + (size_t)n * NN_;
  const _Float16* arl = Al + (size_t)n * NN_;
  float mcur = -1e30f, lsum = 0.f, oacc = 0.f;
  for (int j = 0; j < C; j++) {
    float sv = CandV[(size_t)n * CAND_CAP + j];
    if (!(sv > thr)) continue;
    int p = CandP[(size_t)n * CAND_CAP + j];
    const _Float16* rh = Rth + (size_t)p * NN_;
    const _Float16* rl = Rtl + (size_t)p * NN_;
    float d = 0.f;
#pragma unroll
    for (int it = 0; it < 8; it++) {
      int m = it * 512 + lane * 8;
      f16x8 a8 = *(const f16x8*)&arh[m];
      f16x8 l8 = *(const f16x8*)&arl[m];
      f16x8 c8 = *(const f16x8*)&rh[m];
      f16x8 e8 = *(const f16x8*)&rl[m];
#pragma unroll
      for (int e = 0; e < 8; e++)
        d += ((float)a8[e] + (float)l8[e]) * ((float)c8[e] + (float)e8[e]);
    }
    for (int off = 32; off > 0; off >>= 1) d += __shfl_xor(d, off, 64);
    float vval = (lane < 32) ? Vf[(size_t)p * DM_ + h * 32 + lane] : 0.f;
    float nm = fmaxf(mcur, d);
    float alpha = __expf(mcur - nm);
    float w = __expf(d - nm);
    lsum = lsum * alpha + w;
    oacc = oacc * alpha + w * vval;
    mcur = nm;
  }
  if (lane < 32) out[(size_t)n * DM_ + h * 32 + lane] = oacc / lsum;
}

// ---------------------------------------------------------------------------
extern "C" void kernel_launch(void* const* d_in, const int* in_sizes, int n_in,
                              void* d_out, int out_size, void* d_ws, size_t ws_size,
                              hipStream_t stream) {
  const float* inQ = (const float*)d_in[0];
  const float* inK = (const float*)d_in[1];
  const float* inV = (const float*)d_in[2];
  // d_in[3] = adj_matrix: dead code in the reference
  const float* dist = (const float*)d_in[4];
  const float* WQ = (const float*)d_in[5];
  const float* WK = (const float*)d_in[6];
  const float* WV = (const float*)d_in[7];
  float* out = (float*)d_out;

  const size_t ND = (size_t)NN_ * DM_;   // 1M
  const size_t NSQ = (size_t)NN_ * NN_;  // 16.7M
  // ws layout (~157 MiB total; 212 MiB proven available in round 1):
  float* Vf = (float*)d_ws;              // 4 MiB
  ushort_t* Q1 = (ushort_t*)(Vf + ND);   // 2 MiB each
  ushort_t* Q2 = Q1 + ND;
  ushort_t* K1 = Q2 + ND;
  ushort_t* K2 = K1 + ND;
  _Float16* Rth = (_Float16*)(K2 + ND);  // 32 MiB each
  _Float16* Rtl = Rth + NSQ;
  _Float16* Ah = Rtl + NSQ;              // per-head reuse, 32 MiB each
  _Float16* Al = Ah + NSQ;
  int* CandP = (int*)(Al + NSQ);         // 8 MiB
  float* CandV = (float*)(CandP + (size_t)NN_ * CAND_CAP);  // 8 MiB
  int* rowCnt = (int*)(CandV + (size_t)NN_ * CAND_CAP);     // 16 KiB
  float* rowMax = (float*)(rowCnt + NN_);                   // 16 KiB

  rescale_kernel<<<dim3(64, 64), 256, 0, stream>>>(dist, Rth, Rtl);
  proj_kernel<<<dim3(4, 64), 256, 0, stream>>>(inQ, WQ, (float*)nullptr, Q1, Q2);
  proj_kernel<<<dim3(4, 64), 256, 0, stream>>>(inK, WK, (float*)nullptr, K1, K2);
  proj_kernel<<<dim3(4, 64), 256, 0, stream>>>(inV, WV, Vf, (ushort_t*)nullptr, (ushort_t*)nullptr);
  for (int h = 0; h < 8; h++) {
    qk_kernel<<<dim3(64, 64), 256, 0, stream>>>(Q1, Q2, K1, K2, Ah, Al, rowMax, rowCnt, h);
    sgemm_kernel<<<dim3(32, 32), 256, 0, stream>>>(Ah, Rth, rowMax, rowCnt, CandP, CandV);
    refine_kernel<<<1024, 256, 0, stream>>>(CandP, CandV, rowCnt, rowMax, Ah, Al, Rth, Rtl, Vf, out, h);
  }
}

// Round 7
// 2705.783 us; speedup vs baseline: 3.8179x; 3.8179x over previous
//
#include <hip/hip_runtime.h>
#include <stdint.h>

#define NN_ 4096
#define DM_ 256

typedef unsigned short ushort_t;
typedef __bf16 bf16x8 __attribute__((ext_vector_type(8)));
typedef _Float16 f16x8 __attribute__((ext_vector_type(8)));
typedef float f32x4 __attribute__((ext_vector_type(4)));

__device__ __forceinline__ unsigned short f32_to_bf16(float x) {
  unsigned int u = __float_as_uint(x);
  unsigned int r = u + 0x7FFFu + ((u >> 16) & 1u);   // RNE
  return (unsigned short)(r >> 16);
}
__device__ __forceinline__ float bf16_to_f32(unsigned short h) {
  return __uint_as_float(((unsigned int)h) << 16);
}

// global -> LDS direct (16B/lane). LDS dest is wave-uniform base + lane*16.
__device__ __forceinline__ void async_cp16(const void* g, void* l) {
  auto gp = reinterpret_cast<__attribute__((address_space(1))) unsigned int*>(
      reinterpret_cast<uintptr_t>(g));
  auto lp = reinterpret_cast<__attribute__((address_space(3))) unsigned int*>(
      reinterpret_cast<uintptr_t>(l));
  __builtin_amdgcn_global_load_lds(gp, lp, 16, 0, 0);
}

// ---------------------------------------------------------------------------
// Kernel 1: Rt = rescale(dist)^T as fp16 hi/lo pair. Rt[p][m] = f(dist[m][p]).
// ---------------------------------------------------------------------------
__global__ __launch_bounds__(256) void rescale_kernel(const float* __restrict__ dist,
                                                      _Float16* __restrict__ Rth,
                                                      _Float16* __restrict__ Rtl) {
  __shared__ float tile[64][65];
  const int m0 = blockIdx.y * 64;
  const int p0 = blockIdx.x * 64;
  const int t = threadIdx.x;
  const int c = t & 63;
  const int rg = t >> 6;
  const float C = 3.718281828459045f;  // 1 + e
  for (int i = 0; i < 16; i++) {
    int ml = rg * 16 + i;
    float d = dist[(size_t)(m0 + ml) * NN_ + p0 + c];
    tile[c][ml] = C / (1.0f + expf(1.0f - d));  // store transposed into LDS
  }
  __syncthreads();
  for (int i = 0; i < 16; i++) {
    int pl = rg * 16 + i;
    float v = tile[pl][c];
    _Float16 hv = (_Float16)v;
    size_t o = (size_t)(p0 + pl) * NN_ + m0 + c;
    Rth[o] = hv;
    Rtl[o] = (_Float16)(v - (float)hv);
  }
}

// ---------------------------------------------------------------------------
// Kernel 2: O = X @ W^T (fp32 accum). Optional fp32 out, optional bf16 hi/lo.
// ---------------------------------------------------------------------------
__global__ __launch_bounds__(256) void proj_kernel(const float* __restrict__ X,
                                                   const float* __restrict__ W,
                                                   float* __restrict__ Of,
                                                   ushort_t* __restrict__ O1,
                                                   ushort_t* __restrict__ O2) {
  __shared__ float Xs[64][33];
  __shared__ float Ws[64][33];
  const int m0 = blockIdx.y * 64;
  const int n0 = blockIdx.x * 64;
  const int t = threadIdx.x;
  const int tm = t >> 4, tn = t & 15;
  float acc[4][4] = {};
  for (int k0 = 0; k0 < DM_; k0 += 32) {
    for (int q = 0; q < 2; q++) {
      int id = t + q * 256;
      int row = id >> 3;
      int c4 = (id & 7) * 4;
      float4 vx = *(const float4*)&X[(size_t)(m0 + row) * DM_ + k0 + c4];
      Xs[row][c4] = vx.x; Xs[row][c4 + 1] = vx.y; Xs[row][c4 + 2] = vx.z; Xs[row][c4 + 3] = vx.w;
      float4 vw = *(const float4*)&W[(size_t)(n0 + row) * DM_ + k0 + c4];
      Ws[row][c4] = vw.x; Ws[row][c4 + 1] = vw.y; Ws[row][c4 + 2] = vw.z; Ws[row][c4 + 3] = vw.w;
    }
    __syncthreads();
    for (int kk = 0; kk < 32; kk++) {
      float xi[4], wj[4];
      for (int i = 0; i < 4; i++) xi[i] = Xs[tm * 4 + i][kk];
      for (int j = 0; j < 4; j++) wj[j] = Ws[tn * 4 + j][kk];
      for (int i = 0; i < 4; i++)
        for (int j = 0; j < 4; j++) acc[i][j] += xi[i] * wj[j];
    }
    __syncthreads();
  }
  for (int i = 0; i < 4; i++)
    for (int j = 0; j < 4; j++) {
      size_t o = (size_t)(m0 + tm * 4 + i) * DM_ + n0 + tn * 4 + j;
      float v = acc[i][j];
      if (Of != nullptr) Of[o] = v;
      if (O1 != nullptr) {
        unsigned short hh = f32_to_bf16(v);
        O1[o] = hh;
        O2[o] = f32_to_bf16(v - bf16_to_f32(hh));
      }
    }
}

// ---------------------------------------------------------------------------
// Kernel 3: per head, A = relu(Q_h K_h^T)/sqrt(32), 3-product bf16 (exact-ish),
// output as fp16 hi/lo pair. Block (0,0) also zeroes rowMax for this head.
// ---------------------------------------------------------------------------
__global__ __launch_bounds__(256) void qk_kernel(const ushort_t* __restrict__ Q1,
                                                 const ushort_t* __restrict__ Q2,
                                                 const ushort_t* __restrict__ K1,
                                                 const ushort_t* __restrict__ K2,
                                                 _Float16* __restrict__ Ah,
                                                 _Float16* __restrict__ Al,
                                                 float* __restrict__ rowMax, int h) {
  const int n0 = blockIdx.y * 64;  // rows (n, from Q)
  const int m0 = blockIdx.x * 64;  // cols (m, from K)
  const int t = threadIdx.x;
  if (blockIdx.x == 0 && blockIdx.y == 0) {
    for (int i = t; i < NN_; i += 256) rowMax[i] = 0.f;
  }
  const int wave = t >> 6, lane = t & 63;
  const int wm = wave >> 1, wn = wave & 1;
  const int r16 = lane & 15, quad = lane >> 4;
  const int ho = h * 32 + quad * 8;
  f32x4 acc[2][2] = {};
  bf16x8 a1[2], a2[2], b1[2], b2[2];
  for (int i = 0; i < 2; i++) {
    int row = n0 + wm * 32 + i * 16 + r16;
    a1[i] = *(const bf16x8*)&Q1[(size_t)row * DM_ + ho];
    a2[i] = *(const bf16x8*)&Q2[(size_t)row * DM_ + ho];
  }
  for (int j = 0; j < 2; j++) {
    int col = m0 + wn * 32 + j * 16 + r16;
    b1[j] = *(const bf16x8*)&K1[(size_t)col * DM_ + ho];
    b2[j] = *(const bf16x8*)&K2[(size_t)col * DM_ + ho];
  }
  for (int i = 0; i < 2; i++)
    for (int j = 0; j < 2; j++) {
      acc[i][j] = __builtin_amdgcn_mfma_f32_16x16x32_bf16(a1[i], b1[j], acc[i][j], 0, 0, 0);
      acc[i][j] = __builtin_amdgcn_mfma_f32_16x16x32_bf16(a1[i], b2[j], acc[i][j], 0, 0, 0);
      acc[i][j] = __builtin_amdgcn_mfma_f32_16x16x32_bf16(a2[i], b1[j], acc[i][j], 0, 0, 0);
    }
  const float scale = 0.17677669529663688f;  // 1/sqrt(32)
  for (int i = 0; i < 2; i++)
    for (int j = 0; j < 2; j++)
      for (int r = 0; r < 4; r++) {
        int row = n0 + wm * 32 + i * 16 + quad * 4 + r;  // C/D: col=lane&15, row=quad*4+reg
        int col = m0 + wn * 32 + j * 16 + r16;
        float w = acc[i][j][r] * scale;
        w = w > 0.f ? w : 0.f;
        _Float16 hh = (_Float16)w;
        size_t o = (size_t)row * NN_ + col;
        Ah[o] = hh;
        Al[o] = (_Float16)(w - (float)hh);
      }
}

// ---------------------------------------------------------------------------
// Kernel 4: S~ = Ah @ Rth^T (NT, K=4096), fp16 MFMA, BK=64, 128x128 tile,
// fp16 out. LDS chunk-XOR swizzle (HW-proven in round 6): 16B chunk c of row
// r lives at slot c^(r&7) -> fragment reads hit all 8 bank groups, 2 lanes
// each (free). Staging fetches global chunk (lane&7)^srow so data lands
// identically. Epilogue: per-row atomicMax into rowMax (single atomic per
// (block,row) -- round-5-proven benign) + fp16 tile store.
// ---------------------------------------------------------------------------
__global__ __launch_bounds__(256) void sgemm_kernel(const _Float16* __restrict__ Ah,
                                                    const _Float16* __restrict__ Rth,
                                                    _Float16* __restrict__ Sh,
                                                    float* __restrict__ rowMax) {
  __shared__ _Float16 sA[128 * 64], sB[128 * 64];  // 16 KB each
  const int m0 = blockIdx.y * 128;
  const int p0 = blockIdx.x * 128;
  const int t = threadIdx.x;
  const int wave = t >> 6, lane = t & 63;
  const int wm = wave >> 1, wn = wave & 1;
  const int r16 = lane & 15, quad = lane >> 4;
  const int srow = lane >> 3;            // 0..7 (row within 8-row staging slab)
  const int cg = (lane & 7) ^ srow;      // global 16B chunk this lane fetches
  f32x4 acc[4][4] = {};
  for (int k0 = 0; k0 < NN_; k0 += 64) {
    for (int tt = 0; tt < 4; tt++) {
      int rl = wave * 32 + tt * 8;       // wave-uniform slab base row
      async_cp16(&Ah[(size_t)(m0 + rl + srow) * NN_ + k0 + cg * 8], &sA[rl * 64]);
      async_cp16(&Rth[(size_t)(p0 + rl + srow) * NN_ + k0 + cg * 8], &sB[rl * 64]);
    }
    __syncthreads();
    f16x8 af[4][2], bg[4][2];
    for (int i = 0; i < 4; i++) {
      int r = wm * 64 + i * 16 + r16;
      int s0 = quad ^ (r & 7);
      int s1 = (4 + quad) ^ (r & 7);
      af[i][0] = *(const f16x8*)&sA[r * 64 + s0 * 8];
      af[i][1] = *(const f16x8*)&sA[r * 64 + s1 * 8];
    }
    for (int j = 0; j < 4; j++) {
      int r = wn * 64 + j * 16 + r16;
      int s0 = quad ^ (r & 7);
      int s1 = (4 + quad) ^ (r & 7);
      bg[j][0] = *(const f16x8*)&sB[r * 64 + s0 * 8];
      bg[j][1] = *(const f16x8*)&sB[r * 64 + s1 * 8];
    }
    for (int i = 0; i < 4; i++)
      for (int j = 0; j < 4; j++) {
        acc[i][j] = __builtin_amdgcn_mfma_f32_16x16x32_f16(af[i][0], bg[j][0], acc[i][j], 0, 0, 0);
        acc[i][j] = __builtin_amdgcn_mfma_f32_16x16x32_f16(af[i][1], bg[j][1], acc[i][j], 0, 0, 0);
      }
    __syncthreads();
  }
  // epilogue: per-row max -> atomicMax, then fp16 store of the tile
  for (int i = 0; i < 4; i++)
    for (int r = 0; r < 4; r++) {
      float mv = fmaxf(fmaxf(acc[i][0][r], acc[i][1][r]),
                       fmaxf(acc[i][2][r], acc[i][3][r]));
      for (int off = 1; off < 16; off <<= 1) mv = fmaxf(mv, __shfl_xor(mv, off, 64));
      if (r16 == 0) {
        int row = m0 + wm * 64 + i * 16 + quad * 4 + r;
        atomicMax((unsigned int*)&rowMax[row], __float_as_uint(mv));
      }
    }
  for (int i = 0; i < 4; i++)
    for (int j = 0; j < 4; j++)
      for (int r = 0; r < 4; r++) {
        int row = m0 + wm * 64 + i * 16 + quad * 4 + r;
        int col = p0 + wn * 64 + j * 16 + r16;
        Sh[(size_t)row * NN_ + col] = (_Float16)acc[i][j][r];
      }
}

// ---------------------------------------------------------------------------
// Kernel 5: one wave per row. Single pass over fp16 S~ row collecting
// candidates (S~ > rowMax-16), then exact fp32 dots (A pair x Rt pair),
// flash-style online softmax + PV, all in registers.
// ---------------------------------------------------------------------------
__global__ __launch_bounds__(256) void refine_kernel(const _Float16* __restrict__ Sh,
                                                     const float* __restrict__ rowMax,
                                                     const _Float16* __restrict__ Ah,
                                                     const _Float16* __restrict__ Al,
                                                     const _Float16* __restrict__ Rth,
                                                     const _Float16* __restrict__ Rtl,
                                                     const float* __restrict__ Vf,
                                                     float* __restrict__ out, int h) {
  __shared__ int plist[4][64];
  __shared__ int cnt[4];
  const int t = threadIdx.x;
  const int wave = t >> 6, lane = t & 63;
  const int n = blockIdx.x * 4 + wave;
  if (lane == 0) cnt[wave] = 0;
  __syncthreads();
  const float thr = rowMax[n] - 16.0f;
  const _Float16* srow = Sh + (size_t)n * NN_;
  for (int it = 0; it < 8; it++) {
    f16x8 v = *(const f16x8*)&srow[it * 512 + lane * 8];
#pragma unroll
    for (int e = 0; e < 8; e++) {
      if ((float)v[e] > thr) {
        int idx = atomicAdd(&cnt[wave], 1);
        if (idx < 64) plist[wave][idx] = it * 512 + lane * 8 + e;
      }
    }
  }
  __syncthreads();
  int C = cnt[wave];
  if (C > 64) C = 64;
  const _Float16* arh = Ah + (size_t)n * NN_;
  const _Float16* arl = Al + (size_t)n * NN_;
  float mcur = -1e30f, lsum = 0.f, oacc = 0.f;
  for (int j = 0; j < C; j++) {
    int p = plist[wave][j];
    const _Float16* rh = Rth + (size_t)p * NN_;
    const _Float16* rl = Rtl + (size_t)p * NN_;
    float d = 0.f;
#pragma unroll
    for (int it = 0; it < 8; it++) {
      int m = it * 512 + lane * 8;
      f16x8 a8 = *(const f16x8*)&arh[m];
      f16x8 l8 = *(const f16x8*)&arl[m];
      f16x8 c8 = *(const f16x8*)&rh[m];
      f16x8 e8 = *(const f16x8*)&rl[m];
#pragma unroll
      for (int e = 0; e < 8; e++)
        d += ((float)a8[e] + (float)l8[e]) * ((float)c8[e] + (float)e8[e]);
    }
    for (int off = 32; off > 0; off >>= 1) d += __shfl_xor(d, off, 64);
    float vval = (lane < 32) ? Vf[(size_t)p * DM_ + h * 32 + lane] : 0.f;
    float nm = fmaxf(mcur, d);
    float alpha = __expf(mcur - nm);
    float w = __expf(d - nm);
    lsum = lsum * alpha + w;
    oacc = oacc * alpha + w * vval;
    mcur = nm;
  }
  if (lane < 32) out[(size_t)n * DM_ + h * 32 + lane] = oacc / lsum;
}

// ---------------------------------------------------------------------------
extern "C" void kernel_launch(void* const* d_in, const int* in_sizes, int n_in,
                              void* d_out, int out_size, void* d_ws, size_t ws_size,
                              hipStream_t stream) {
  const float* inQ = (const float*)d_in[0];
  const float* inK = (const float*)d_in[1];
  const float* inV = (const float*)d_in[2];
  // d_in[3] = adj_matrix: dead code in the reference
  const float* dist = (const float*)d_in[4];
  const float* WQ = (const float*)d_in[5];
  const float* WK = (const float*)d_in[6];
  const float* WV = (const float*)d_in[7];
  float* out = (float*)d_out;

  const size_t ND = (size_t)NN_ * DM_;   // 1M
  const size_t NSQ = (size_t)NN_ * NN_;  // 16.7M
  // ws layout (~172 MiB total; 212 MiB proven available in round 1):
  float* Vf = (float*)d_ws;              // 4 MiB
  ushort_t* Q1 = (ushort_t*)(Vf + ND);   // 2 MiB each
  ushort_t* Q2 = Q1 + ND;
  ushort_t* K1 = Q2 + ND;
  ushort_t* K2 = K1 + ND;
  _Float16* Rth = (_Float16*)(K2 + ND);  // 32 MiB each
  _Float16* Rtl = Rth + NSQ;
  _Float16* Ah = Rtl + NSQ;              // per-head reuse, 32 MiB each
  _Float16* Al = Ah + NSQ;
  _Float16* Sh = Al + NSQ;               // 32 MiB
  float* rowMax = (float*)(Sh + NSQ);    // 16 KiB

  rescale_kernel<<<dim3(64, 64), 256, 0, stream>>>(dist, Rth, Rtl);
  proj_kernel<<<dim3(4, 64), 256, 0, stream>>>(inQ, WQ, (float*)nullptr, Q1, Q2);
  proj_kernel<<<dim3(4, 64), 256, 0, stream>>>(inK, WK, (float*)nullptr, K1, K2);
  proj_kernel<<<dim3(4, 64), 256, 0, stream>>>(inV, WV, Vf, (ushort_t*)nullptr, (ushort_t*)nullptr);
  for (int h = 0; h < 8; h++) {
    qk_kernel<<<dim3(64, 64), 256, 0, stream>>>(Q1, Q2, K1, K2, Ah, Al, rowMax, h);
    sgemm_kernel<<<dim3(32, 32), 256, 0, stream>>>(Ah, Rth, Sh, rowMax);
    refine_kernel<<<1024, 256, 0, stream>>>(Sh, rowMax, Ah, Al, Rth, Rtl, Vf, out, h);
  }
}

// Round 8
// 2202.123 us; speedup vs baseline: 4.6911x; 1.2287x over previous
//
#include <hip/hip_runtime.h>
#include <stdint.h>

#define NN_ 4096
#define DM_ 256

typedef unsigned short ushort_t;
typedef __bf16 bf16x8 __attribute__((ext_vector_type(8)));
typedef _Float16 f16x8 __attribute__((ext_vector_type(8)));
typedef float f32x4 __attribute__((ext_vector_type(4)));

__device__ __forceinline__ unsigned short f32_to_bf16(float x) {
  unsigned int u = __float_as_uint(x);
  unsigned int r = u + 0x7FFFu + ((u >> 16) & 1u);   // RNE
  return (unsigned short)(r >> 16);
}
__device__ __forceinline__ float bf16_to_f32(unsigned short h) {
  return __uint_as_float(((unsigned int)h) << 16);
}

// global -> LDS direct (16B/lane). LDS dest is wave-uniform base + lane*16.
__device__ __forceinline__ void async_cp16(const void* g, void* l) {
  auto gp = reinterpret_cast<__attribute__((address_space(1))) unsigned int*>(
      reinterpret_cast<uintptr_t>(g));
  auto lp = reinterpret_cast<__attribute__((address_space(3))) unsigned int*>(
      reinterpret_cast<uintptr_t>(l));
  __builtin_amdgcn_global_load_lds(gp, lp, 16, 0, 0);
}

// ---------------------------------------------------------------------------
// Kernel 1: Rt = rescale(dist)^T as fp16 hi/lo pair. Rt[p][m] = f(dist[m][p]).
// ---------------------------------------------------------------------------
__global__ __launch_bounds__(256) void rescale_kernel(const float* __restrict__ dist,
                                                      _Float16* __restrict__ Rth,
                                                      _Float16* __restrict__ Rtl) {
  __shared__ float tile[64][65];
  const int m0 = blockIdx.y * 64;
  const int p0 = blockIdx.x * 64;
  const int t = threadIdx.x;
  const int c = t & 63;
  const int rg = t >> 6;
  const float C = 3.718281828459045f;  // 1 + e
  for (int i = 0; i < 16; i++) {
    int ml = rg * 16 + i;
    float d = dist[(size_t)(m0 + ml) * NN_ + p0 + c];
    tile[c][ml] = C / (1.0f + expf(1.0f - d));  // store transposed into LDS
  }
  __syncthreads();
  for (int i = 0; i < 16; i++) {
    int pl = rg * 16 + i;
    float v = tile[pl][c];
    _Float16 hv = (_Float16)v;
    size_t o = (size_t)(p0 + pl) * NN_ + m0 + c;
    Rth[o] = hv;
    Rtl[o] = (_Float16)(v - (float)hv);
  }
}

// ---------------------------------------------------------------------------
// Kernel 2: O = X @ W^T (fp32 accum). Optional fp32 out, optional bf16 hi/lo.
// ---------------------------------------------------------------------------
__global__ __launch_bounds__(256) void proj_kernel(const float* __restrict__ X,
                                                   const float* __restrict__ W,
                                                   float* __restrict__ Of,
                                                   ushort_t* __restrict__ O1,
                                                   ushort_t* __restrict__ O2) {
  __shared__ float Xs[64][33];
  __shared__ float Ws[64][33];
  const int m0 = blockIdx.y * 64;
  const int n0 = blockIdx.x * 64;
  const int t = threadIdx.x;
  const int tm = t >> 4, tn = t & 15;
  float acc[4][4] = {};
  for (int k0 = 0; k0 < DM_; k0 += 32) {
    for (int q = 0; q < 2; q++) {
      int id = t + q * 256;
      int row = id >> 3;
      int c4 = (id & 7) * 4;
      float4 vx = *(const float4*)&X[(size_t)(m0 + row) * DM_ + k0 + c4];
      Xs[row][c4] = vx.x; Xs[row][c4 + 1] = vx.y; Xs[row][c4 + 2] = vx.z; Xs[row][c4 + 3] = vx.w;
      float4 vw = *(const float4*)&W[(size_t)(n0 + row) * DM_ + k0 + c4];
      Ws[row][c4] = vw.x; Ws[row][c4 + 1] = vw.y; Ws[row][c4 + 2] = vw.z; Ws[row][c4 + 3] = vw.w;
    }
    __syncthreads();
    for (int kk = 0; kk < 32; kk++) {
      float xi[4], wj[4];
      for (int i = 0; i < 4; i++) xi[i] = Xs[tm * 4 + i][kk];
      for (int j = 0; j < 4; j++) wj[j] = Ws[tn * 4 + j][kk];
      for (int i = 0; i < 4; i++)
        for (int j = 0; j < 4; j++) acc[i][j] += xi[i] * wj[j];
    }
    __syncthreads();
  }
  for (int i = 0; i < 4; i++)
    for (int j = 0; j < 4; j++) {
      size_t o = (size_t)(m0 + tm * 4 + i) * DM_ + n0 + tn * 4 + j;
      float v = acc[i][j];
      if (Of != nullptr) Of[o] = v;
      if (O1 != nullptr) {
        unsigned short hh = f32_to_bf16(v);
        O1[o] = hh;
        O2[o] = f32_to_bf16(v - bf16_to_f32(hh));
      }
    }
}

// ---------------------------------------------------------------------------
// Kernel 3: per head, A = relu(Q_h K_h^T)/sqrt(32), 3-product bf16 (exact-ish),
// output as fp16 hi/lo pair. Block (0,0) also zeroes rowMax for this head.
// ---------------------------------------------------------------------------
__global__ __launch_bounds__(256) void qk_kernel(const ushort_t* __restrict__ Q1,
                                                 const ushort_t* __restrict__ Q2,
                                                 const ushort_t* __restrict__ K1,
                                                 const ushort_t* __restrict__ K2,
                                                 _Float16* __restrict__ Ah,
                                                 _Float16* __restrict__ Al,
                                                 float* __restrict__ rowMax, int h) {
  const int n0 = blockIdx.y * 64;  // rows (n, from Q)
  const int m0 = blockIdx.x * 64;  // cols (m, from K)
  const int t = threadIdx.x;
  if (blockIdx.x == 0 && blockIdx.y == 0) {
    for (int i = t; i < NN_; i += 256) rowMax[i] = 0.f;
  }
  const int wave = t >> 6, lane = t & 63;
  const int wm = wave >> 1, wn = wave & 1;
  const int r16 = lane & 15, quad = lane >> 4;
  const int ho = h * 32 + quad * 8;
  f32x4 acc[2][2] = {};
  bf16x8 a1[2], a2[2], b1[2], b2[2];
  for (int i = 0; i < 2; i++) {
    int row = n0 + wm * 32 + i * 16 + r16;
    a1[i] = *(const bf16x8*)&Q1[(size_t)row * DM_ + ho];
    a2[i] = *(const bf16x8*)&Q2[(size_t)row * DM_ + ho];
  }
  for (int j = 0; j < 2; j++) {
    int col = m0 + wn * 32 + j * 16 + r16;
    b1[j] = *(const bf16x8*)&K1[(size_t)col * DM_ + ho];
    b2[j] = *(const bf16x8*)&K2[(size_t)col * DM_ + ho];
  }
  for (int i = 0; i < 2; i++)
    for (int j = 0; j < 2; j++) {
      acc[i][j] = __builtin_amdgcn_mfma_f32_16x16x32_bf16(a1[i], b1[j], acc[i][j], 0, 0, 0);
      acc[i][j] = __builtin_amdgcn_mfma_f32_16x16x32_bf16(a1[i], b2[j], acc[i][j], 0, 0, 0);
      acc[i][j] = __builtin_amdgcn_mfma_f32_16x16x32_bf16(a2[i], b1[j], acc[i][j], 0, 0, 0);
    }
  const float scale = 0.17677669529663688f;  // 1/sqrt(32)
  for (int i = 0; i < 2; i++)
    for (int j = 0; j < 2; j++)
      for (int r = 0; r < 4; r++) {
        int row = n0 + wm * 32 + i * 16 + quad * 4 + r;  // C/D: col=lane&15, row=quad*4+reg
        int col = m0 + wn * 32 + j * 16 + r16;
        float w = acc[i][j][r] * scale;
        w = w > 0.f ? w : 0.f;
        _Float16 hh = (_Float16)w;
        size_t o = (size_t)row * NN_ + col;
        Ah[o] = hh;
        Al[o] = (_Float16)(w - (float)hh);
      }
}

// ---------------------------------------------------------------------------
// Kernel 4: S~ = Ah @ Rth^T (NT, K=4096), fp16 MFMA, BK=64, 128x128 tile,
// fp16 out. LDS chunk-XOR swizzle (HW-proven): chunk c of row r at slot
// c^(r&7); staging fetches global chunk (lane&7)^srow. Epilogue: per-row
// atomicMax into rowMax + fp16 tile store.
// ---------------------------------------------------------------------------
__global__ __launch_bounds__(256) void sgemm_kernel(const _Float16* __restrict__ Ah,
                                                    const _Float16* __restrict__ Rth,
                                                    _Float16* __restrict__ Sh,
                                                    float* __restrict__ rowMax) {
  __shared__ _Float16 sA[128 * 64], sB[128 * 64];  // 16 KB each
  const int m0 = blockIdx.y * 128;
  const int p0 = blockIdx.x * 128;
  const int t = threadIdx.x;
  const int wave = t >> 6, lane = t & 63;
  const int wm = wave >> 1, wn = wave & 1;
  const int r16 = lane & 15, quad = lane >> 4;
  const int srow = lane >> 3;            // 0..7 (row within 8-row staging slab)
  const int cg = (lane & 7) ^ srow;      // global 16B chunk this lane fetches
  f32x4 acc[4][4] = {};
  for (int k0 = 0; k0 < NN_; k0 += 64) {
    for (int tt = 0; tt < 4; tt++) {
      int rl = wave * 32 + tt * 8;       // wave-uniform slab base row
      async_cp16(&Ah[(size_t)(m0 + rl + srow) * NN_ + k0 + cg * 8], &sA[rl * 64]);
      async_cp16(&Rth[(size_t)(p0 + rl + srow) * NN_ + k0 + cg * 8], &sB[rl * 64]);
    }
    __syncthreads();
    f16x8 af[4][2], bg[4][2];
    for (int i = 0; i < 4; i++) {
      int r = wm * 64 + i * 16 + r16;
      int s0 = quad ^ (r & 7);
      int s1 = (4 + quad) ^ (r & 7);
      af[i][0] = *(const f16x8*)&sA[r * 64 + s0 * 8];
      af[i][1] = *(const f16x8*)&sA[r * 64 + s1 * 8];
    }
    for (int j = 0; j < 4; j++) {
      int r = wn * 64 + j * 16 + r16;
      int s0 = quad ^ (r & 7);
      int s1 = (4 + quad) ^ (r & 7);
      bg[j][0] = *(const f16x8*)&sB[r * 64 + s0 * 8];
      bg[j][1] = *(const f16x8*)&sB[r * 64 + s1 * 8];
    }
    for (int i = 0; i < 4; i++)
      for (int j = 0; j < 4; j++) {
        acc[i][j] = __builtin_amdgcn_mfma_f32_16x16x32_f16(af[i][0], bg[j][0], acc[i][j], 0, 0, 0);
        acc[i][j] = __builtin_amdgcn_mfma_f32_16x16x32_f16(af[i][1], bg[j][1], acc[i][j], 0, 0, 0);
      }
    __syncthreads();
  }
  // epilogue: per-row max -> atomicMax, then fp16 store of the tile
  for (int i = 0; i < 4; i++)
    for (int r = 0; r < 4; r++) {
      float mv = fmaxf(fmaxf(acc[i][0][r], acc[i][1][r]),
                       fmaxf(acc[i][2][r], acc[i][3][r]));
      for (int off = 1; off < 16; off <<= 1) mv = fmaxf(mv, __shfl_xor(mv, off, 64));
      if (r16 == 0) {
        int row = m0 + wm * 64 + i * 16 + quad * 4 + r;
        atomicMax((unsigned int*)&rowMax[row], __float_as_uint(mv));
      }
    }
  for (int i = 0; i < 4; i++)
    for (int j = 0; j < 4; j++)
      for (int r = 0; r < 4; r++) {
        int row = m0 + wm * 64 + i * 16 + quad * 4 + r;
        int col = p0 + wn * 64 + j * 16 + r16;
        Sh[(size_t)row * NN_ + col] = (_Float16)acc[i][j][r];
      }
}

// ---------------------------------------------------------------------------
// Kernel 5: one BLOCK (4 waves) per row. Each wave scans 1/4 of the S~ row
// for candidates (S~ > rowMax-16) into a shared list; candidates are then
// distributed across waves (j = wave, wave+4, ...), each wave keeping its own
// online-softmax state (m, l, o); final flash-merge via LDS. Exact candidate
// scores: fp32 dot of (Ah+Al) x (Rth+Rtl), 64-lane shuffle reduce.
// ---------------------------------------------------------------------------
__global__ __launch_bounds__(256) void refine_kernel(const _Float16* __restrict__ Sh,
                                                     const float* __restrict__ rowMax,
                                                     const _Float16* __restrict__ Ah,
                                                     const _Float16* __restrict__ Al,
                                                     const _Float16* __restrict__ Rth,
                                                     const _Float16* __restrict__ Rtl,
                                                     const float* __restrict__ Vf,
                                                     float* __restrict__ out, int h) {
  __shared__ int plist[64];
  __shared__ int cnt;
  __shared__ float mW[4], lW[4];
  __shared__ float oW[4][32];
  const int t = threadIdx.x;
  const int wave = t >> 6, lane = t & 63;
  const int n = blockIdx.x;
  if (t == 0) cnt = 0;
  __syncthreads();
  const float thr = rowMax[n] - 16.0f;
  const _Float16* srow = Sh + (size_t)n * NN_;
  // each wave scans 2 of the 8 chunks (1024 elements)
  for (int q = 0; q < 2; q++) {
    int it = wave * 2 + q;
    f16x8 v = *(const f16x8*)&srow[it * 512 + lane * 8];
#pragma unroll
    for (int e = 0; e < 8; e++) {
      if ((float)v[e] > thr) {
        int idx = atomicAdd(&cnt, 1);
        if (idx < 64) plist[idx] = it * 512 + lane * 8 + e;
      }
    }
  }
  __syncthreads();
  int C = cnt;
  if (C > 64) C = 64;
  const _Float16* arh = Ah + (size_t)n * NN_;
  const _Float16* arl = Al + (size_t)n * NN_;
  float mcur = -1e30f, lsum = 0.f, oacc = 0.f;
  for (int j = wave; j < C; j += 4) {
    int p = plist[j];
    const _Float16* rh = Rth + (size_t)p * NN_;
    const _Float16* rl = Rtl + (size_t)p * NN_;
    float d = 0.f;
#pragma unroll
    for (int it = 0; it < 8; it++) {
      int m = it * 512 + lane * 8;
      f16x8 a8 = *(const f16x8*)&arh[m];
      f16x8 l8 = *(const f16x8*)&arl[m];
      f16x8 c8 = *(const f16x8*)&rh[m];
      f16x8 e8 = *(const f16x8*)&rl[m];
#pragma unroll
      for (int e = 0; e < 8; e++)
        d += ((float)a8[e] + (float)l8[e]) * ((float)c8[e] + (float)e8[e]);
    }
    for (int off = 32; off > 0; off >>= 1) d += __shfl_xor(d, off, 64);
    float vval = (lane < 32) ? Vf[(size_t)p * DM_ + h * 32 + lane] : 0.f;
    float nm = fmaxf(mcur, d);
    float alpha = __expf(mcur - nm);
    float w = __expf(d - nm);
    lsum = lsum * alpha + w;
    oacc = oacc * alpha + w * vval;
    mcur = nm;
  }
  if (lane == 0) { mW[wave] = mcur; lW[wave] = lsum; }
  if (lane < 32) oW[wave][lane] = oacc;
  __syncthreads();
  if (wave == 0 && lane < 32) {
    float M = fmaxf(fmaxf(mW[0], mW[1]), fmaxf(mW[2], mW[3]));
    float l = 0.f, o = 0.f;
#pragma unroll
    for (int w = 0; w < 4; w++) {
      float al = __expf(mW[w] - M);
      l += lW[w] * al;
      o += oW[w][lane] * al;
    }
    out[(size_t)n * DM_ + h * 32 + lane] = o / l;
  }
}

// ---------------------------------------------------------------------------
extern "C" void kernel_launch(void* const* d_in, const int* in_sizes, int n_in,
                              void* d_out, int out_size, void* d_ws, size_t ws_size,
                              hipStream_t stream) {
  const float* inQ = (const float*)d_in[0];
  const float* inK = (const float*)d_in[1];
  const float* inV = (const float*)d_in[2];
  // d_in[3] = adj_matrix: dead code in the reference
  const float* dist = (const float*)d_in[4];
  const float* WQ = (const float*)d_in[5];
  const float* WK = (const float*)d_in[6];
  const float* WV = (const float*)d_in[7];
  float* out = (float*)d_out;

  const size_t ND = (size_t)NN_ * DM_;   // 1M
  const size_t NSQ = (size_t)NN_ * NN_;  // 16.7M
  // ws layout (~172 MiB total; 212 MiB proven available in round 1):
  float* Vf = (float*)d_ws;              // 4 MiB
  ushort_t* Q1 = (ushort_t*)(Vf + ND);   // 2 MiB each
  ushort_t* Q2 = Q1 + ND;
  ushort_t* K1 = Q2 + ND;
  ushort_t* K2 = K1 + ND;
  _Float16* Rth = (_Float16*)(K2 + ND);  // 32 MiB each
  _Float16* Rtl = Rth + NSQ;
  _Float16* Ah = Rtl + NSQ;              // per-head reuse, 32 MiB each
  _Float16* Al = Ah + NSQ;
  _Float16* Sh = Al + NSQ;               // 32 MiB
  float* rowMax = (float*)(Sh + NSQ);    // 16 KiB

  rescale_kernel<<<dim3(64, 64), 256, 0, stream>>>(dist, Rth, Rtl);
  proj_kernel<<<dim3(4, 64), 256, 0, stream>>>(inQ, WQ, (float*)nullptr, Q1, Q2);
  proj_kernel<<<dim3(4, 64), 256, 0, stream>>>(inK, WK, (float*)nullptr, K1, K2);
  proj_kernel<<<dim3(4, 64), 256, 0, stream>>>(inV, WV, Vf, (ushort_t*)nullptr, (ushort_t*)nullptr);
  for (int h = 0; h < 8; h++) {
    qk_kernel<<<dim3(64, 64), 256, 0, stream>>>(Q1, Q2, K1, K2, Ah, Al, rowMax, h);
    sgemm_kernel<<<dim3(32, 32), 256, 0, stream>>>(Ah, Rth, Sh, rowMax);
    refine_kernel<<<NN_, 256, 0, stream>>>(Sh, rowMax, Ah, Al, Rth, Rtl, Vf, out, h);
  }
}